// Round 1
// baseline (735.512 us; speedup 1.0000x reference)
//
#include <hip/hip_runtime.h>
#include <math.h>

#define IN_DIM 256
#define OUT_DIM 64

// order-preserving float <-> uint mapping for atomicMax on floats
__device__ __forceinline__ unsigned f2ord(float f) {
    unsigned u = __float_as_uint(f);
    return (u & 0x80000000u) ? ~u : (u | 0x80000000u);
}
__device__ __forceinline__ float ord2f(unsigned u) {
    return __uint_as_float((u & 0x80000000u) ? (u & 0x7FFFFFFFu) : ~u);
}

__device__ __forceinline__ float edge_score(float x) {
    float e = x > 0.0f ? x : 0.01f * x;   // leaky_relu, slope 0.01
    if (e == 0.0f) e = -1000.0f;          // where(e==0, -1000, e)
    return e;
}

// z = h @ W_fc  (W_fc staged in LDS), s[row] = dot(z[row], W_attn[:64])
__global__ __launch_bounds__(256) void gemm_s_kernel(
    const float* __restrict__ h, const float* __restrict__ Wfc,
    const float* __restrict__ Wattn, float* __restrict__ z,
    float* __restrict__ s, int n_rows)
{
    __shared__ float Wlds[IN_DIM * OUT_DIM];   // 64 KB
    const int tid = threadIdx.x;
    {
        const float4* W4 = (const float4*)Wfc;
        float4* L4 = (float4*)Wlds;
        #pragma unroll
        for (int i = 0; i < (IN_DIM * OUT_DIM / 4) / 256; ++i)
            L4[tid + i * 256] = W4[tid + i * 256];
    }
    __syncthreads();

    const int lane = tid & 63;
    const int wv = tid >> 6;
    const float a = Wattn[lane];
    const int row0 = blockIdx.x * 16 + wv * 4;

    const int r0 = min(row0 + 0, n_rows - 1);
    const int r1 = min(row0 + 1, n_rows - 1);
    const int r2 = min(row0 + 2, n_rows - 1);
    const int r3 = min(row0 + 3, n_rows - 1);

    const float4* h4 = (const float4*)h;
    const size_t b0 = (size_t)r0 * (IN_DIM / 4);
    const size_t b1 = (size_t)r1 * (IN_DIM / 4);
    const size_t b2 = (size_t)r2 * (IN_DIM / 4);
    const size_t b3 = (size_t)r3 * (IN_DIM / 4);

    float acc0 = 0.f, acc1 = 0.f, acc2 = 0.f, acc3 = 0.f;
    #pragma unroll 4
    for (int k4 = 0; k4 < IN_DIM / 4; ++k4) {
        float4 h0 = h4[b0 + k4];
        float4 h1 = h4[b1 + k4];
        float4 h2 = h4[b2 + k4];
        float4 h3 = h4[b3 + k4];
        float w0 = Wlds[(k4 * 4 + 0) * OUT_DIM + lane];
        float w1 = Wlds[(k4 * 4 + 1) * OUT_DIM + lane];
        float w2 = Wlds[(k4 * 4 + 2) * OUT_DIM + lane];
        float w3 = Wlds[(k4 * 4 + 3) * OUT_DIM + lane];
        acc0 = fmaf(h0.w, w3, fmaf(h0.z, w2, fmaf(h0.y, w1, fmaf(h0.x, w0, acc0))));
        acc1 = fmaf(h1.w, w3, fmaf(h1.z, w2, fmaf(h1.y, w1, fmaf(h1.x, w0, acc1))));
        acc2 = fmaf(h2.w, w3, fmaf(h2.z, w2, fmaf(h2.y, w1, fmaf(h2.x, w0, acc2))));
        acc3 = fmaf(h3.w, w3, fmaf(h3.z, w2, fmaf(h3.y, w1, fmaf(h3.x, w0, acc3))));
    }

    if (row0 + 0 < n_rows) z[(size_t)(row0 + 0) * OUT_DIM + lane] = acc0;
    if (row0 + 1 < n_rows) z[(size_t)(row0 + 1) * OUT_DIM + lane] = acc1;
    if (row0 + 2 < n_rows) z[(size_t)(row0 + 2) * OUT_DIM + lane] = acc2;
    if (row0 + 3 < n_rows) z[(size_t)(row0 + 3) * OUT_DIM + lane] = acc3;

    float p0 = acc0 * a, p1 = acc1 * a, p2 = acc2 * a, p3 = acc3 * a;
    #pragma unroll
    for (int off = 32; off > 0; off >>= 1) {
        p0 += __shfl_down(p0, off);
        p1 += __shfl_down(p1, off);
        p2 += __shfl_down(p2, off);
        p3 += __shfl_down(p3, off);
    }
    if (lane == 0) {
        if (row0 + 0 < n_rows) s[row0 + 0] = p0;
        if (row0 + 1 < n_rows) s[row0 + 1] = p1;
        if (row0 + 2 < n_rows) s[row0 + 2] = p2;
        if (row0 + 3 < n_rows) s[row0 + 3] = p3;
    }
}

__global__ __launch_bounds__(256) void emax_kernel(
    const int* __restrict__ src, const int* __restrict__ dst,
    const float* __restrict__ s, unsigned* __restrict__ emax_ord, int n_edges)
{
    int i = blockIdx.x * blockDim.x + threadIdx.x;
    int stride = gridDim.x * blockDim.x;
    for (; i < n_edges; i += stride) {
        float e = edge_score(s[src[i]]);
        atomicMax(emax_ord + dst[i], f2ord(e));
    }
}

__global__ __launch_bounds__(256) void denom_kernel(
    const int* __restrict__ src, const int* __restrict__ dst,
    const float* __restrict__ s, const unsigned* __restrict__ emax_ord,
    float* __restrict__ denom, int n_edges)
{
    int i = blockIdx.x * blockDim.x + threadIdx.x;
    int stride = gridDim.x * blockDim.x;
    for (; i < n_edges; i += stride) {
        int dt = dst[i];
        float e = edge_score(s[src[i]]);
        float m = ord2f(emax_ord[dt]);
        if (!(m >= -3.4e38f && m <= 3.4e38f)) m = 0.0f;  // !isfinite -> 0
        float w = __expf(e - m);
        atomicAdd(denom + dt, w);
    }
}

// one wave per edge: lane d adds alpha * z[src][d] into out[dst][d]
__global__ __launch_bounds__(256) void scatter_kernel(
    const int* __restrict__ src, const int* __restrict__ dst,
    const float* __restrict__ s, const unsigned* __restrict__ emax_ord,
    const float* __restrict__ denom, const float* __restrict__ z,
    float* __restrict__ out, int n_edges)
{
    int wave_id = (blockIdx.x * blockDim.x + threadIdx.x) >> 6;
    int lane = threadIdx.x & 63;
    int n_waves = (gridDim.x * blockDim.x) >> 6;
    for (int i = wave_id; i < n_edges; i += n_waves) {
        int sr = src[i];
        int dt = dst[i];
        float e = edge_score(s[sr]);
        float m = ord2f(emax_ord[dt]);
        if (!(m >= -3.4e38f && m <= 3.4e38f)) m = 0.0f;
        float w = __expf(e - m);
        float d = fmaxf(denom[dt], 1e-20f);
        float alpha = w / d;
        atomicAdd(out + (size_t)dt * OUT_DIM + lane,
                  alpha * z[(size_t)sr * OUT_DIM + lane]);
    }
}

extern "C" void kernel_launch(void* const* d_in, const int* in_sizes, int n_in,
                              void* d_out, int out_size, void* d_ws, size_t ws_size,
                              hipStream_t stream)
{
    const float* h     = (const float*)d_in[0];
    const int*   esrc  = (const int*)d_in[1];
    const int*   edst  = (const int*)d_in[2];
    // d_in[3] = n_pnodes scalar on device; derive from out_size instead
    const float* Wfc   = (const float*)d_in[4];
    const float* Wattn = (const float*)d_in[5];
    float* out = (float*)d_out;

    const int n_w = in_sizes[0] / IN_DIM;   // 100000
    const int n_e = in_sizes[1];            // 1600000
    const int n_p = out_size / OUT_DIM;     // 50000

    // workspace layout
    float*    z     = (float*)d_ws;                       // n_w * 64
    float*    s     = z + (size_t)n_w * OUT_DIM;          // n_w
    unsigned* emax  = (unsigned*)(s + n_w);               // n_p
    float*    denom = (float*)(emax + n_p);               // n_p

    hipMemsetAsync(d_out, 0, (size_t)out_size * sizeof(float), stream);
    hipMemsetAsync(emax, 0, (size_t)n_p * sizeof(unsigned), stream);  // unmaps to -NaN => empty-segment path
    hipMemsetAsync(denom, 0, (size_t)n_p * sizeof(float), stream);

    const int gemm_blocks = (n_w + 15) / 16;
    gemm_s_kernel<<<gemm_blocks, 256, 0, stream>>>(h, Wfc, Wattn, z, s, n_w);
    emax_kernel<<<2048, 256, 0, stream>>>(esrc, edst, s, emax, n_e);
    denom_kernel<<<2048, 256, 0, stream>>>(esrc, edst, s, emax, denom, n_e);
    scatter_kernel<<<8192, 256, 0, stream>>>(esrc, edst, s, emax, denom, z, out, n_e);
}

// Round 2
// 617.310 us; speedup vs baseline: 1.1915x; 1.1915x over previous
//
#include <hip/hip_runtime.h>
#include <math.h>

#define IN_DIM 256
#define OUT_DIM 64

__device__ __forceinline__ float edge_score(float x) {
    float e = x > 0.0f ? x : 0.01f * x;   // leaky_relu, slope 0.01
    if (e == 0.0f) e = -1000.0f;          // where(e==0, -1000, e)
    return e;
}

// z = h @ W_fc  (W_fc staged in LDS), s[row] = dot(z[row], W_attn[:64])
__global__ __launch_bounds__(256) void gemm_s_kernel(
    const float* __restrict__ h, const float* __restrict__ Wfc,
    const float* __restrict__ Wattn, float* __restrict__ z,
    float* __restrict__ s, int n_rows)
{
    __shared__ float Wlds[IN_DIM * OUT_DIM];   // 64 KB
    const int tid = threadIdx.x;
    {
        const float4* W4 = (const float4*)Wfc;
        float4* L4 = (float4*)Wlds;
        #pragma unroll
        for (int i = 0; i < (IN_DIM * OUT_DIM / 4) / 256; ++i)
            L4[tid + i * 256] = W4[tid + i * 256];
    }
    __syncthreads();

    const int lane = tid & 63;
    const int wv = tid >> 6;
    const float a = Wattn[lane];
    const int row0 = blockIdx.x * 16 + wv * 4;

    const int r0 = min(row0 + 0, n_rows - 1);
    const int r1 = min(row0 + 1, n_rows - 1);
    const int r2 = min(row0 + 2, n_rows - 1);
    const int r3 = min(row0 + 3, n_rows - 1);

    const float4* h4 = (const float4*)h;
    const size_t b0 = (size_t)r0 * (IN_DIM / 4);
    const size_t b1 = (size_t)r1 * (IN_DIM / 4);
    const size_t b2 = (size_t)r2 * (IN_DIM / 4);
    const size_t b3 = (size_t)r3 * (IN_DIM / 4);

    float acc0 = 0.f, acc1 = 0.f, acc2 = 0.f, acc3 = 0.f;
    #pragma unroll 4
    for (int k4 = 0; k4 < IN_DIM / 4; ++k4) {
        float4 h0 = h4[b0 + k4];
        float4 h1 = h4[b1 + k4];
        float4 h2 = h4[b2 + k4];
        float4 h3 = h4[b3 + k4];
        float w0 = Wlds[(k4 * 4 + 0) * OUT_DIM + lane];
        float w1 = Wlds[(k4 * 4 + 1) * OUT_DIM + lane];
        float w2 = Wlds[(k4 * 4 + 2) * OUT_DIM + lane];
        float w3 = Wlds[(k4 * 4 + 3) * OUT_DIM + lane];
        acc0 = fmaf(h0.w, w3, fmaf(h0.z, w2, fmaf(h0.y, w1, fmaf(h0.x, w0, acc0))));
        acc1 = fmaf(h1.w, w3, fmaf(h1.z, w2, fmaf(h1.y, w1, fmaf(h1.x, w0, acc1))));
        acc2 = fmaf(h2.w, w3, fmaf(h2.z, w2, fmaf(h2.y, w1, fmaf(h2.x, w0, acc2))));
        acc3 = fmaf(h3.w, w3, fmaf(h3.z, w2, fmaf(h3.y, w1, fmaf(h3.x, w0, acc3))));
    }

    if (row0 + 0 < n_rows) z[(size_t)(row0 + 0) * OUT_DIM + lane] = acc0;
    if (row0 + 1 < n_rows) z[(size_t)(row0 + 1) * OUT_DIM + lane] = acc1;
    if (row0 + 2 < n_rows) z[(size_t)(row0 + 2) * OUT_DIM + lane] = acc2;
    if (row0 + 3 < n_rows) z[(size_t)(row0 + 3) * OUT_DIM + lane] = acc3;

    float p0 = acc0 * a, p1 = acc1 * a, p2 = acc2 * a, p3 = acc3 * a;
    #pragma unroll
    for (int off = 32; off > 0; off >>= 1) {
        p0 += __shfl_down(p0, off);
        p1 += __shfl_down(p1, off);
        p2 += __shfl_down(p2, off);
        p3 += __shfl_down(p3, off);
    }
    if (lane == 0) {
        if (row0 + 0 < n_rows) s[row0 + 0] = p0;
        if (row0 + 1 < n_rows) s[row0 + 1] = p1;
        if (row0 + 2 < n_rows) s[row0 + 2] = p2;
        if (row0 + 3 < n_rows) s[row0 + 3] = p3;
    }
}

// count[dst]++
__global__ __launch_bounds__(256) void hist_kernel(
    const int* __restrict__ dst, int* __restrict__ cnt, int n_edges)
{
    int i = blockIdx.x * blockDim.x + threadIdx.x;
    int stride = gridDim.x * blockDim.x;
    for (; i < n_edges; i += stride) atomicAdd(cnt + dst[i], 1);
}

// single-block exclusive scan of cnt[0..n) -> off[] and woff[]; off[n]=total
__global__ __launch_bounds__(1024) void scan_kernel(
    const int* __restrict__ cnt, int* __restrict__ off, int* __restrict__ woff, int n)
{
    __shared__ int ssum[1024];
    const int t = threadIdx.x;
    const int chunk = (n + 1023) >> 10;
    const int b = t * chunk;
    const int e = min(b + chunk, n);
    int local = 0;
    for (int i = b; i < e; ++i) local += cnt[i];
    ssum[t] = local;
    __syncthreads();
    // Hillis-Steele inclusive scan
    for (int d = 1; d < 1024; d <<= 1) {
        int v = (t >= d) ? ssum[t - d] : 0;
        __syncthreads();
        ssum[t] += v;
        __syncthreads();
    }
    int run = ssum[t] - local;   // exclusive prefix for this thread's chunk
    for (int i = b; i < e; ++i) {
        off[i] = run; woff[i] = run;
        run += cnt[i];
    }
    if (t == 1023) off[n] = ssum[1023];
}

// bin edges by dst; also precompute per-edge score e
__global__ __launch_bounds__(256) void bin_kernel(
    const int* __restrict__ src, const int* __restrict__ dst,
    const float* __restrict__ s, int* __restrict__ woff,
    int* __restrict__ sorted_src, float* __restrict__ sorted_e, int n_edges)
{
    int i = blockIdx.x * blockDim.x + threadIdx.x;
    int stride = gridDim.x * blockDim.x;
    for (; i < n_edges; i += stride) {
        int sr = src[i];
        float e = edge_score(s[sr]);
        int pos = atomicAdd(woff + dst[i], 1);
        sorted_src[pos] = sr;
        sorted_e[pos] = e;
    }
}

// one wave per pnode: softmax over its contiguous edge segment + weighted z-sum
__global__ __launch_bounds__(256) void segment_kernel(
    const int* __restrict__ off, const int* __restrict__ sorted_src,
    const float* __restrict__ sorted_e, const float* __restrict__ z,
    float* __restrict__ out, int n_pnodes)
{
    const int p = blockIdx.x * 4 + (threadIdx.x >> 6);
    if (p >= n_pnodes) return;
    const int lane = threadIdx.x & 63;
    const int beg = off[p];
    const int end = off[p + 1];

    if (beg == end) {                       // empty segment -> zero row
        out[(size_t)p * OUT_DIM + lane] = 0.0f;
        return;
    }

    // pass 1: segment max
    float m = -INFINITY;
    for (int j = beg + lane; j < end; j += 64) m = fmaxf(m, sorted_e[j]);
    #pragma unroll
    for (int o = 32; o > 0; o >>= 1) m = fmaxf(m, __shfl_xor(m, o));
    // m is finite for non-empty segments (reference's isfinite fixup not needed)

    // pass 2: w = exp(e - m); denom; weighted accumulation over dims
    float acc = 0.0f, dsum = 0.0f;
    for (int c = beg; c < end; c += 64) {
        const int j = c + lane;
        const bool v = j < end;
        float w = 0.0f;
        int sr = 0;
        if (v) {
            w = __expf(sorted_e[j] - m);
            sr = sorted_src[j];
        }
        dsum += w;
        const int cn = min(64, end - c);
        for (int t = 0; t < cn; ++t) {
            float wt = __shfl(w, t);
            int st = __shfl(sr, t);
            acc = fmaf(wt, z[(size_t)st * OUT_DIM + lane], acc);
        }
    }
    #pragma unroll
    for (int o = 32; o > 0; o >>= 1) dsum += __shfl_xor(dsum, o);
    out[(size_t)p * OUT_DIM + lane] = acc / fmaxf(dsum, 1e-20f);
}

extern "C" void kernel_launch(void* const* d_in, const int* in_sizes, int n_in,
                              void* d_out, int out_size, void* d_ws, size_t ws_size,
                              hipStream_t stream)
{
    const float* h     = (const float*)d_in[0];
    const int*   esrc  = (const int*)d_in[1];
    const int*   edst  = (const int*)d_in[2];
    const float* Wfc   = (const float*)d_in[4];
    const float* Wattn = (const float*)d_in[5];
    float* out = (float*)d_out;

    const int n_w = in_sizes[0] / IN_DIM;   // 100000
    const int n_e = in_sizes[1];            // 1600000
    const int n_p = out_size / OUT_DIM;     // 50000

    // workspace layout (floats/ints, 4B each)
    float* z          = (float*)d_ws;                         // n_w * 64
    float* s          = z + (size_t)n_w * OUT_DIM;            // n_w
    float* sorted_e   = s + n_w;                              // n_e
    int*   sorted_src = (int*)(sorted_e + n_e);               // n_e
    int*   cnt        = sorted_src + n_e;                     // n_p
    int*   off        = cnt + n_p;                            // n_p + 1
    int*   woff       = off + n_p + 1;                        // n_p

    hipMemsetAsync(cnt, 0, (size_t)n_p * sizeof(int), stream);

    const int gemm_blocks = (n_w + 15) / 16;
    gemm_s_kernel<<<gemm_blocks, 256, 0, stream>>>(h, Wfc, Wattn, z, s, n_w);
    hist_kernel<<<2048, 256, 0, stream>>>(edst, cnt, n_e);
    scan_kernel<<<1, 1024, 0, stream>>>(cnt, off, woff, n_p);
    bin_kernel<<<2048, 256, 0, stream>>>(esrc, edst, s, woff, sorted_src, sorted_e, n_e);
    segment_kernel<<<(n_p + 3) / 4, 256, 0, stream>>>(off, sorted_src, sorted_e, z, out, n_p);
}